// Round 7
// baseline (1288.151 us; speedup 1.0000x reference)
//
#include <hip/hip_runtime.h>
#include <hip/hip_bf16.h>

// Elman RNN: B=128, T=256, I=512, H=1024
//   Phase 1: xp[b,h] per t  (MFMA GEMM, bf16, 32x128 tiles)
//   Phase 2: ONE persistent kernel (R6 structure + LDS-traffic halving):
//     - R6 PMC: per-CU LDS read BW is the step floor (8 waves x 32KB A-tile
//       = 256KB/step ~ 3000cy). Fix: 4 waves x 32 cols (TWO resident W
//       fragment sets = 256 VGPR W per lane) -> 128KB/step, each A-frag
//       register feeds 2 MFMAs.
//     - 256 thr = 1 wave/SIMD; __launch_bounds__(256,1) -> 512-VGPR cap,
//       no spill (R3 lesson; spill tell = FETCH_SIZE balloon).
//     - xp for step t+1 prefetched into regs under the MFMA phase (removes
//       L3 latency from the post-scatter vmcnt(0) drain).
//     - XCD-local groups g=bid&7 (R6-proven: FETCH 298->82MB).
//     - fan-in-8 barrier, padded-pitch LDS, states-after-arrive (proven).
// Precision: bf16 inputs, fp32 MFMA accumulate, fp32 tanh, fp32 output.

#define B_SZ 128
#define T_SZ 256
#define I_SZ 512
#define H_SZ 1024

#define GROUPS 8
#define BLK_PG 8                       // blocks per group (128 cols each)
#define GRID_P (GROUPS * BLK_PG)       // 64 persistent blocks
#define THR_P  256                     // 4 waves: 2x16 cols x K=1024 each
#define PITCH  2080                    // LDS row pitch (2048 + 32 pad)

typedef __bf16 bf16x8 __attribute__((ext_vector_type(8)));
typedef __bf16 bf16x4 __attribute__((ext_vector_type(4)));
typedef float f32x4 __attribute__((ext_vector_type(4)));
typedef unsigned long long u64;

__device__ __forceinline__ float fast_tanh(float x) {
    // exact at +-inf saturation, ~1e-6 abs err; bf16 noise dominates anyway
    return 1.0f - 2.0f / (__expf(2.0f * x) + 1.0f);
}

// ---------------- fp32 -> bf16 convert (vectorized x4) ----------------
__global__ void cvt_kernel(const float* __restrict__ src, __bf16* __restrict__ dst, int n4) {
    int i = blockIdx.x * blockDim.x + threadIdx.x;
    if (i < n4) {
        float4 v = reinterpret_cast<const float4*>(src)[i];
        bf16x4 o;
        o[0] = (__bf16)v.x; o[1] = (__bf16)v.y; o[2] = (__bf16)v.z; o[3] = (__bf16)v.w;
        reinterpret_cast<bf16x4*>(dst)[i] = o;
    }
}

// ---------------- input projection -> xp stored [T,B,H] ----------------
// 32 bt-rows x 128 cols per block, 8 waves, 2 row-subtiles per wave.
__global__ __launch_bounds__(512) void proj_kernel(const __bf16* __restrict__ x,
                                                   const __bf16* __restrict__ wih,
                                                   const float* __restrict__ bih,
                                                   __bf16* __restrict__ xp) {
    const int m0   = blockIdx.x * 32;      // bt row tile
    const int n0   = blockIdx.y * 128;
    const int lane = threadIdx.x & 63;
    const int wave = threadIdx.x >> 6;     // 0..7
    const int lm   = lane & 15;
    const int quad = lane >> 4;
    const int nw   = n0 + wave * 16;

    f32x4 acc0 = {0.f, 0.f, 0.f, 0.f};
    f32x4 acc1 = {0.f, 0.f, 0.f, 0.f};
    const __bf16* arow0 = x   + (size_t)(m0 + lm) * I_SZ + quad * 8;
    const __bf16* arow1 = arow0 + 16 * I_SZ;
    const __bf16* brow  = wih + (size_t)(nw + lm) * I_SZ + quad * 8;
#pragma unroll 4
    for (int k = 0; k < I_SZ; k += 32) {
        bf16x8 b  = *reinterpret_cast<const bf16x8*>(brow  + k);
        bf16x8 a0 = *reinterpret_cast<const bf16x8*>(arow0 + k);
        bf16x8 a1 = *reinterpret_cast<const bf16x8*>(arow1 + k);
        acc0 = __builtin_amdgcn_mfma_f32_16x16x32_bf16(a0, b, acc0, 0, 0, 0);
        acc1 = __builtin_amdgcn_mfma_f32_16x16x32_bf16(a1, b, acc1, 0, 0, 0);
    }
    const int col  = nw + lm;
    const float bias = bih[col];
#pragma unroll
    for (int r = 0; r < 4; ++r) {
        int row = m0 + quad * 4 + r;       // bt index: b = row>>8, t = row&255
        xp[((size_t)(row & (T_SZ - 1)) * B_SZ + (row >> 8)) * H_SZ + col] = (__bf16)(acc0[r] + bias);
        row += 16;
        xp[((size_t)(row & (T_SZ - 1)) * B_SZ + (row >> 8)) * H_SZ + col] = (__bf16)(acc1[r] + bias);
    }
}

// ---------------- persistent recurrence ----------------
// 64 blocks x 256 threads (4 waves). block = 16 rows x 128 cols.
// wave = TWO 16-col tiles (cols w*16.. and 64+w*16..), K=1024 each.
// group g = bid&7 (XCD-local), chunk cb = bid>>3. Fan-in-8 counter barrier.
__global__ __launch_bounds__(THR_P, 1) void rnn_persist(const float* __restrict__ whh,
                                                        const __bf16* __restrict__ xp,
                                                        const float* __restrict__ bhh,
                                                        __bf16* __restrict__ hA,
                                                        __bf16* __restrict__ hB,
                                                        float* __restrict__ states,
                                                        float* __restrict__ hlast,
                                                        unsigned* __restrict__ cnt) {
    __shared__ __align__(16) char   lds_raw[16 * PITCH];  // padded-pitch h tile (~32.5 KB)
    __shared__ __align__(16) __bf16 htile[16 * 128];      // 4 KB packed next-h

    const int tid  = threadIdx.x;
    const int lane = tid & 63;
    const int wave = tid >> 6;             // 0..3
    const int lm   = lane & 15;
    const int quad = lane >> 4;
    const int bid  = blockIdx.x;
    const int g    = bid & 7;              // batch group == XCD (round-robin dispatch)
    const int cb   = bid >> 3;             // col chunk within group
    const int r0   = g * 16;               // first batch row of group
    const int colA = cb * 128 + wave * 16 + lm;
    const int colB = colA + 64;

    // ---- W_hh resident: 2 x (16 cols x K=1024) per wave, fp32->bf16 inline ----
    bf16x8 wfA[32], wfB[32];
    {
        const float* wpA = whh + (size_t)colA * H_SZ + quad * 8;
        const float* wpB = whh + (size_t)colB * H_SZ + quad * 8;
#pragma unroll
        for (int i = 0; i < 32; ++i) {
            f32x4 lo = *reinterpret_cast<const f32x4*>(wpA + i * 32);
            f32x4 hi = *reinterpret_cast<const f32x4*>(wpA + i * 32 + 4);
            bf16x8 o;
            o[0] = (__bf16)lo[0]; o[1] = (__bf16)lo[1];
            o[2] = (__bf16)lo[2]; o[3] = (__bf16)lo[3];
            o[4] = (__bf16)hi[0]; o[5] = (__bf16)hi[1];
            o[6] = (__bf16)hi[2]; o[7] = (__bf16)hi[3];
            wfA[i] = o;
            lo = *reinterpret_cast<const f32x4*>(wpB + i * 32);
            hi = *reinterpret_cast<const f32x4*>(wpB + i * 32 + 4);
            o[0] = (__bf16)lo[0]; o[1] = (__bf16)lo[1];
            o[2] = (__bf16)lo[2]; o[3] = (__bf16)lo[3];
            o[4] = (__bf16)hi[0]; o[5] = (__bf16)hi[1];
            o[6] = (__bf16)hi[2]; o[7] = (__bf16)hi[3];
            wfB[i] = o;
        }
    }
    const float biasA = bhh[colA];
    const float biasB = bhh[colB];
    unsigned* my_cnt = cnt + g * 32;       // per-group counter, 128B apart

    size_t stA[4], stB[4];
#pragma unroll
    for (int r = 0; r < 4; ++r) {
        stA[r] = (size_t)(r0 + quad * 4 + r) * T_SZ * H_SZ + colA;
        stB[r] = (size_t)(r0 + quad * 4 + r) * T_SZ * H_SZ + colB;
    }

    // ---- xp for t=0 preloaded ----
    float xcA[4], xcB[4], xnA[4], xnB[4];
#pragma unroll
    for (int r = 0; r < 4; ++r) {
        const __bf16* xr = xp + (size_t)(r0 + quad * 4 + r) * H_SZ;
        xcA[r] = (float)xr[colA];
        xcB[r] = (float)xr[colB];
    }

    for (int t = 0; t < T_SZ; ++t) {
        const __bf16* cur = (t & 1) ? hB : hA;
        __bf16*       nxt = (t & 1) ? hA : hB;

        // ---- cooperative h load (critical path): 32 KB via 8B atomics ----
        const u64* src = (const u64*)(cur + (size_t)r0 * H_SZ);
        u64 v[16];
#pragma unroll
        for (int i = 0; i < 16; ++i)
            v[i] = __hip_atomic_load(src + tid + i * THR_P,
                                     __ATOMIC_RELAXED, __HIP_MEMORY_SCOPE_AGENT);

        // ---- scatter to padded-pitch LDS: thread writes col tid*8B of row i ----
#pragma unroll
        for (int i = 0; i < 16; ++i)
            *(u64*)(lds_raw + i * PITCH + tid * 8) = v[i];
        __syncthreads();

        // ---- xp prefetch for t+1 (flies under the MFMA phase) ----
        {
            int tn = (t + 1 < T_SZ) ? t + 1 : t;
            const __bf16* xbase = xp + (size_t)tn * B_SZ * H_SZ;
#pragma unroll
            for (int r = 0; r < 4; ++r) {
                const __bf16* xr = xbase + (size_t)(r0 + quad * 4 + r) * H_SZ;
                xnA[r] = (float)xr[colA];
                xnB[r] = (float)xr[colB];
            }
        }

        // ---- MFMA: each A-frag feeds BOTH col tiles; 4 acc chains ----
        f32x4 aA0 = {0.f, 0.f, 0.f, 0.f};
        f32x4 aA1 = {0.f, 0.f, 0.f, 0.f};
        f32x4 aB0 = {0.f, 0.f, 0.f, 0.f};
        f32x4 aB1 = {0.f, 0.f, 0.f, 0.f};
#pragma unroll
        for (int i = 0; i < 32; i += 2) {
            bf16x8 a0 = *reinterpret_cast<const bf16x8*>(
                lds_raw + lm * PITCH + i * 64 + quad * 16);
            bf16x8 a1 = *reinterpret_cast<const bf16x8*>(
                lds_raw + lm * PITCH + (i + 1) * 64 + quad * 16);
            aA0 = __builtin_amdgcn_mfma_f32_16x16x32_bf16(a0, wfA[i],     aA0, 0, 0, 0);
            aB0 = __builtin_amdgcn_mfma_f32_16x16x32_bf16(a0, wfB[i],     aB0, 0, 0, 0);
            aA1 = __builtin_amdgcn_mfma_f32_16x16x32_bf16(a1, wfA[i + 1], aA1, 0, 0, 0);
            aB1 = __builtin_amdgcn_mfma_f32_16x16x32_bf16(a1, wfB[i + 1], aB1, 0, 0, 0);
        }

        // ---- tanh + pack next-h tile into LDS ----
        float hvA[4], hvB[4];
#pragma unroll
        for (int r = 0; r < 4; ++r) {
            hvA[r] = fast_tanh(aA0[r] + aA1[r] + xcA[r] + biasA);
            hvB[r] = fast_tanh(aB0[r] + aB1[r] + xcB[r] + biasB);
            htile[(quad * 4 + r) * 128 + wave * 16 + lm]      = (__bf16)hvA[r];
            htile[(quad * 4 + r) * 128 + 64 + wave * 16 + lm] = (__bf16)hvB[r];
        }
        __syncthreads();

        if (t < T_SZ - 1) {
            // ---- distributed packed h store: two u64 per thread (4 KB) ----
#pragma unroll
            for (int j = 0; j < 2; ++j) {
                int idx = tid + j * THR_P;     // 0..511
                int row = idx >> 5;            // 32 u64 per 128-col row
                int c8  = idx & 31;
                __hip_atomic_store((u64*)((char*)nxt + (size_t)(r0 + row) * 2048
                                          + cb * 256 + c8 * 8),
                                   ((const u64*)htile)[idx],
                                   __ATOMIC_RELAXED, __HIP_MEMORY_SCOPE_AGENT);
            }
            __syncthreads();               // vmcnt(0) drain before the arrive
            if (tid == 0)
                __hip_atomic_fetch_add(my_cnt, 1u,
                                       __ATOMIC_RELAXED, __HIP_MEMORY_SCOPE_AGENT);
        }

        // ---- fp32 outputs AFTER arrive: HBM latency overlaps the spin ----
#pragma unroll
        for (int r = 0; r < 4; ++r) {
            states[stA[r] + (size_t)t * H_SZ] = hvA[r];
            states[stB[r] + (size_t)t * H_SZ] = hvB[r];
        }
        if (t == T_SZ - 1) {
#pragma unroll
            for (int r = 0; r < 4; ++r) {
                hlast[(size_t)(r0 + quad * 4 + r) * H_SZ + colA] = hvA[r];
                hlast[(size_t)(r0 + quad * 4 + r) * H_SZ + colB] = hvB[r];
            }
        }

        if (t < T_SZ - 1) {
            if (tid == 0) {
                const unsigned target = (unsigned)BLK_PG * (unsigned)(t + 1);
                while (__hip_atomic_load(my_cnt, __ATOMIC_RELAXED,
                                         __HIP_MEMORY_SCOPE_AGENT) < target)
                    __builtin_amdgcn_s_sleep(2);
            }
            __syncthreads();
        }

        // ---- rotate xp double-buffer ----
#pragma unroll
        for (int r = 0; r < 4; ++r) { xcA[r] = xnA[r]; xcB[r] = xnB[r]; }
    }
}

extern "C" void kernel_launch(void* const* d_in, const int* in_sizes, int n_in,
                              void* d_out, int out_size, void* d_ws, size_t ws_size,
                              hipStream_t stream) {
    const float* x    = (const float*)d_in[0];   // [B,T,I]
    const float* Wih  = (const float*)d_in[1];   // [H,I]
    const float* Whh  = (const float*)d_in[2];   // [H,H]
    const float* bih  = (const float*)d_in[3];   // [H]
    const float* bhh  = (const float*)d_in[4];   // [H]

    float* states = (float*)d_out;                               // [B,T,H]
    float* hlast  = (float*)d_out + (size_t)B_SZ * T_SZ * H_SZ;  // [B,H]

    // workspace carve (bytes), all 16B aligned
    char* w = (char*)d_ws;
    __bf16* x_bf   = (__bf16*)w;  w += (size_t)B_SZ * T_SZ * I_SZ * 2;  // 33.5 MB
    __bf16* wih_bf = (__bf16*)w;  w += (size_t)H_SZ * I_SZ * 2;         // 1 MB
    __bf16* xp_bf  = (__bf16*)w;  w += (size_t)B_SZ * T_SZ * H_SZ * 2;  // 67 MB, [T,B,H]
    __bf16* hA     = (__bf16*)w;  w += (size_t)B_SZ * H_SZ * 2;         // 256 KB
    __bf16* hB     = (__bf16*)w;  w += (size_t)B_SZ * H_SZ * 2;         // 256 KB
    unsigned* cnt  = (unsigned*)w; w += 1024;                           // 8 group counters, 128B apart
    (void)ws_size;

    // converts (W_hh converted inline by rnn_persist)
    {
        int n4 = B_SZ * T_SZ * I_SZ / 4;
        cvt_kernel<<<(n4 + 255) / 256, 256, 0, stream>>>(x, x_bf, n4);
    }
    {
        int n4 = H_SZ * I_SZ / 4;
        cvt_kernel<<<(n4 + 255) / 256, 256, 0, stream>>>(Wih, wih_bf, n4);
    }

    // h0 = 0, group counters = 0 (ws is re-poisoned 0xAA before every launch)
    hipMemsetAsync(hA, 0, (size_t)B_SZ * H_SZ * 2, stream);
    hipMemsetAsync(cnt, 0, 1024, stream);

    // input projection: 32x128 tiles
    {
        dim3 grid(B_SZ * T_SZ / 32, H_SZ / 128);  // (1024, 8)
        proj_kernel<<<grid, 512, 0, stream>>>(x_bf, wih_bf, bih, xp_bf);
    }

    // persistent recurrence: 8 XCD-local group chains, fan-in 8 barriers
    rnn_persist<<<GRID_P, THR_P, 0, stream>>>(Whh, xp_bf, bhh, hA, hB,
                                              states, hlast, cnt);
}

// Round 8
// 1154.473 us; speedup vs baseline: 1.1158x; 1.1158x over previous
//
#include <hip/hip_runtime.h>
#include <hip/hip_bf16.h>

// Elman RNN: B=128, T=256, I=512, H=1024
//   Phase 1: xp[b,h] per t. proj v2: B-frags hoisted to VGPRs (64/lane),
//     64-row x 128-col blocks (4 row-subtiles reuse B-regs), (512,2) bound.
//   Phase 2: ONE persistent kernel (R6 8-wave structure, 609us proven) +
//     - SPLIT-K EXCHANGE: 2 counters/group. Producers cb<4 arrive cnt0
//       (h cols 0..511), cb>=4 arrive cnt1. Consumer: spin0 -> issue lo
//       loads -> spin1 (overlaps lo flight) -> issue hi loads -> scatter
//       lo -> sync -> MFMA K-lo (hi drains underneath) -> scatter hi ->
//       sync -> MFMA K-hi. Hides hi-half exchange behind MFMA-lo.
//     - ALL-LANE coalesced spin (1 req/wave), no wake syncthreads.
//     - shfl-pack producer stores (no htile LDS round-trip, one less sync).
//     - R6-proven: XCD-local groups (g=bid&7, FETCH 298->82MB), W_hh
//       resident via (512,2), padded-pitch LDS, states-after-arrive.
//   R7 lesson: 8 waves > 4 waves (latency hiding beats LDS-traffic halving).
// Precision: bf16 inputs, fp32 MFMA accumulate, fp32 tanh, fp32 output.

#define B_SZ 128
#define T_SZ 256
#define I_SZ 512
#define H_SZ 1024

#define GROUPS 8
#define BLK_PG 8                       // blocks per group (128 cols each)
#define GRID_P (GROUPS * BLK_PG)       // 64 persistent blocks
#define THR_P  512                     // 8 waves: 16 cols x K=1024 each
#define PITCH  2080                    // LDS row pitch (2048 + 32 pad)

typedef __bf16 bf16x8 __attribute__((ext_vector_type(8)));
typedef __bf16 bf16x4 __attribute__((ext_vector_type(4)));
typedef float f32x4 __attribute__((ext_vector_type(4)));
typedef unsigned long long u64;

__device__ __forceinline__ float fast_tanh(float x) {
    // exact at +-inf saturation, ~1e-6 abs err; bf16 noise dominates anyway
    return 1.0f - 2.0f / (__expf(2.0f * x) + 1.0f);
}

__device__ __forceinline__ unsigned pack2_bf16(float lo, float hi) {
    union { __bf16 b; unsigned short s; } a, c;
    a.b = (__bf16)lo; c.b = (__bf16)hi;
    return (unsigned)a.s | ((unsigned)c.s << 16);
}

// ---------------- fp32 -> bf16 convert (vectorized x4) ----------------
__global__ void cvt_kernel(const float* __restrict__ src, __bf16* __restrict__ dst, int n4) {
    int i = blockIdx.x * blockDim.x + threadIdx.x;
    if (i < n4) {
        float4 v = reinterpret_cast<const float4*>(src)[i];
        bf16x4 o;
        o[0] = (__bf16)v.x; o[1] = (__bf16)v.y; o[2] = (__bf16)v.z; o[3] = (__bf16)v.w;
        reinterpret_cast<bf16x4*>(dst)[i] = o;
    }
}

// ---------------- input projection -> xp stored [T,B,H] ----------------
// Block = 64 bt-rows x 128 cols, 8 waves. Wave owns 16 cols with its
// B-frags (K=512) HOISTED into 64 VGPRs; 4 row-subtiles reuse them.
__global__ __launch_bounds__(512, 2) void proj_kernel(const __bf16* __restrict__ x,
                                                      const __bf16* __restrict__ wih,
                                                      const float* __restrict__ bih,
                                                      __bf16* __restrict__ xp) {
    const int m0   = blockIdx.x * 64;      // bt row tile
    const int lane = threadIdx.x & 63;
    const int wave = threadIdx.x >> 6;     // 0..7
    const int lm   = lane & 15;
    const int quad = lane >> 4;
    const int col  = blockIdx.y * 128 + wave * 16 + lm;

    // hoist B: 16 cols x K=512 per wave -> 16 frags = 64 VGPRs
    bf16x8 bfrag[16];
    {
        const __bf16* brow = wih + (size_t)col * I_SZ + quad * 8;
#pragma unroll
        for (int c = 0; c < 16; ++c)
            bfrag[c] = *reinterpret_cast<const bf16x8*>(brow + c * 32);
    }
    const float bias = bih[col];

#pragma unroll 1
    for (int s = 0; s < 4; ++s) {
        const __bf16* arow = x + (size_t)(m0 + s * 16 + lm) * I_SZ + quad * 8;
        f32x4 acc = {0.f, 0.f, 0.f, 0.f};
#pragma unroll
        for (int c = 0; c < 16; ++c) {
            bf16x8 a = *reinterpret_cast<const bf16x8*>(arow + c * 32);
            acc = __builtin_amdgcn_mfma_f32_16x16x32_bf16(a, bfrag[c], acc, 0, 0, 0);
        }
#pragma unroll
        for (int r = 0; r < 4; ++r) {
            int row = m0 + s * 16 + quad * 4 + r;   // bt: b = row>>8, t = row&255
            xp[((size_t)(row & (T_SZ - 1)) * B_SZ + (row >> 8)) * H_SZ + col]
                = (__bf16)(acc[r] + bias);
        }
    }
}

// ---------------- persistent recurrence ----------------
// 64 blocks x 512 threads (8 waves). block = 16 rows x 128 cols.
// group g = bid&7 (XCD-local), chunk cb = bid>>3. Split-K dual counters.
__global__ __launch_bounds__(THR_P, 2) void rnn_persist(const float* __restrict__ whh,
                                                        const __bf16* __restrict__ xp,
                                                        const float* __restrict__ bhh,
                                                        __bf16* __restrict__ hA,
                                                        __bf16* __restrict__ hB,
                                                        float* __restrict__ states,
                                                        float* __restrict__ hlast,
                                                        unsigned* __restrict__ cnt) {
    __shared__ __align__(16) char lds_raw[16 * PITCH];  // padded-pitch h tile

    const int tid  = threadIdx.x;
    const int lane = tid & 63;
    const int wave = tid >> 6;             // 0..7
    const int lm   = lane & 15;
    const int quad = lane >> 4;
    const int bid  = blockIdx.x;
    const int g    = bid & 7;              // batch group == XCD (round-robin dispatch)
    const int cb   = bid >> 3;             // col chunk within group
    const int r0   = g * 16;               // first batch row of group
    const int col  = cb * 128 + wave * 16 + lm;

    // ---- W_hh resident: 16 cols x K=1024 per wave, fp32->bf16 inline ----
    bf16x8 wfrag[32];
    {
        const float* wp = whh + (size_t)col * H_SZ + quad * 8;
#pragma unroll
        for (int i = 0; i < 32; ++i) {
            f32x4 lo = *reinterpret_cast<const f32x4*>(wp + i * 32);
            f32x4 hi = *reinterpret_cast<const f32x4*>(wp + i * 32 + 4);
            bf16x8 o;
            o[0] = (__bf16)lo[0]; o[1] = (__bf16)lo[1];
            o[2] = (__bf16)lo[2]; o[3] = (__bf16)lo[3];
            o[4] = (__bf16)hi[0]; o[5] = (__bf16)hi[1];
            o[6] = (__bf16)hi[2]; o[7] = (__bf16)hi[3];
            wfrag[i] = o;
        }
    }
    const float bias = bhh[col];

    unsigned* cnt0 = cnt + g * 64;         // lo-half counter (cols 0..511)
    unsigned* cnt1 = cnt0 + 32;            // hi-half counter (128B apart)
    unsigned* my_cnt = (cb < 4) ? cnt0 : cnt1;

    // t-invariant load/scatter offsets: i<4 lo half, i>=4 hi half
    int g_off[8], l_off[8];
#pragma unroll
    for (int i = 0; i < 8; ++i) {
        int u   = tid + (i & 3) * THR_P;   // 0..2047
        int row = u >> 7;                  // 128 u64 per half-row
        int idx = u & 127;
        g_off[i] = row * 256 + (i >> 2) * 128 + idx;       // u64 units
        l_off[i] = row * PITCH + (i >> 2) * 1024 + idx * 8; // bytes
    }

    size_t st_base[4];
#pragma unroll
    for (int r = 0; r < 4; ++r)
        st_base[r] = (size_t)(r0 + quad * 4 + r) * T_SZ * H_SZ + col;

    for (int t = 0; t < T_SZ; ++t) {
        const __bf16* cur = (t & 1) ? hB : hA;
        __bf16*       nxt = (t & 1) ? hA : hB;
        const unsigned tgt = 4u * (unsigned)t;
        const u64* srcu = (const u64*)(cur + (size_t)r0 * H_SZ);

        // ---- spin lo (all lanes, coalesced), issue lo loads ----
        while (__hip_atomic_load(cnt0, __ATOMIC_RELAXED, __HIP_MEMORY_SCOPE_AGENT) < tgt)
            __builtin_amdgcn_s_sleep(1);
        u64 v[8];
#pragma unroll
        for (int i = 0; i < 4; ++i)
            v[i] = __hip_atomic_load(srcu + g_off[i],
                                     __ATOMIC_RELAXED, __HIP_MEMORY_SCOPE_AGENT);

        // ---- spin hi (overlaps lo flight), issue hi loads ----
        while (__hip_atomic_load(cnt1, __ATOMIC_RELAXED, __HIP_MEMORY_SCOPE_AGENT) < tgt)
            __builtin_amdgcn_s_sleep(1);
#pragma unroll
        for (int i = 4; i < 8; ++i)
            v[i] = __hip_atomic_load(srcu + g_off[i],
                                     __ATOMIC_RELAXED, __HIP_MEMORY_SCOPE_AGENT);

        // ---- xp loads (consumed at tanh; drain under MFMA) ----
        float xv[4];
#pragma unroll
        for (int r = 0; r < 4; ++r)
            xv[r] = (float)xp[(size_t)t * B_SZ * H_SZ
                              + (size_t)(r0 + quad * 4 + r) * H_SZ + col];

        // ---- scatter lo, sync, MFMA K-lo (hi loads drain underneath) ----
#pragma unroll
        for (int i = 0; i < 4; ++i)
            *(u64*)(lds_raw + l_off[i]) = v[i];
        __syncthreads();

        f32x4 acc0 = {0.f, 0.f, 0.f, 0.f};
        f32x4 acc1 = {0.f, 0.f, 0.f, 0.f};
#pragma unroll
        for (int i = 0; i < 16; i += 2) {
            bf16x8 a0 = *reinterpret_cast<const bf16x8*>(
                lds_raw + lm * PITCH + i * 64 + quad * 16);
            bf16x8 a1 = *reinterpret_cast<const bf16x8*>(
                lds_raw + lm * PITCH + (i + 1) * 64 + quad * 16);
            acc0 = __builtin_amdgcn_mfma_f32_16x16x32_bf16(a0, wfrag[i],     acc0, 0, 0, 0);
            acc1 = __builtin_amdgcn_mfma_f32_16x16x32_bf16(a1, wfrag[i + 1], acc1, 0, 0, 0);
        }

        // ---- scatter hi (disjoint LDS region), sync, MFMA K-hi ----
#pragma unroll
        for (int i = 4; i < 8; ++i)
            *(u64*)(lds_raw + l_off[i]) = v[i];
        __syncthreads();
#pragma unroll
        for (int i = 16; i < 32; i += 2) {
            bf16x8 a0 = *reinterpret_cast<const bf16x8*>(
                lds_raw + lm * PITCH + i * 64 + quad * 16);
            bf16x8 a1 = *reinterpret_cast<const bf16x8*>(
                lds_raw + lm * PITCH + (i + 1) * 64 + quad * 16);
            acc0 = __builtin_amdgcn_mfma_f32_16x16x32_bf16(a0, wfrag[i],     acc0, 0, 0, 0);
            acc1 = __builtin_amdgcn_mfma_f32_16x16x32_bf16(a1, wfrag[i + 1], acc1, 0, 0, 0);
        }

        // ---- tanh ----
        float hv[4];
#pragma unroll
        for (int r = 0; r < 4; ++r)
            hv[r] = fast_tanh(acc0[r] + acc1[r] + xv[r] + bias);

        if (t < T_SZ - 1) {
            // ---- shfl-pack: u64 = 4 consecutive cols of one row ----
            u64* nrow = (u64*)nxt;
#pragma unroll
            for (int r = 0; r < 4; ++r) {
                float p1  = __shfl_xor(hv[r], 1, 64);
                unsigned w32 = pack2_bf16(hv[r], p1);          // cols (lm, lm+1) on even lm
                unsigned q32 = (unsigned)__shfl_xor((int)w32, 2, 64); // cols (lm+2, lm+3)
                if ((lm & 3) == 0) {
                    u64 pk = (u64)w32 | ((u64)q32 << 32);
                    __hip_atomic_store(nrow + (size_t)(r0 + quad * 4 + r) * 256
                                            + ((cb * 128 + wave * 16 + lm) >> 2),
                                       pk, __ATOMIC_RELAXED, __HIP_MEMORY_SCOPE_AGENT);
                }
            }
            __syncthreads();               // per-wave vmcnt(0) drain before arrive
            if (tid == 0)
                __hip_atomic_fetch_add(my_cnt, 1u,
                                       __ATOMIC_RELAXED, __HIP_MEMORY_SCOPE_AGENT);
        }

        // ---- fp32 outputs AFTER arrive: HBM latency overlaps next spin ----
#pragma unroll
        for (int r = 0; r < 4; ++r)
            states[st_base[r] + (size_t)t * H_SZ] = hv[r];
        if (t == T_SZ - 1) {
#pragma unroll
            for (int r = 0; r < 4; ++r)
                hlast[(size_t)(r0 + quad * 4 + r) * H_SZ + col] = hv[r];
        }
    }
}

extern "C" void kernel_launch(void* const* d_in, const int* in_sizes, int n_in,
                              void* d_out, int out_size, void* d_ws, size_t ws_size,
                              hipStream_t stream) {
    const float* x    = (const float*)d_in[0];   // [B,T,I]
    const float* Wih  = (const float*)d_in[1];   // [H,I]
    const float* Whh  = (const float*)d_in[2];   // [H,H]
    const float* bih  = (const float*)d_in[3];   // [H]
    const float* bhh  = (const float*)d_in[4];   // [H]

    float* states = (float*)d_out;                               // [B,T,H]
    float* hlast  = (float*)d_out + (size_t)B_SZ * T_SZ * H_SZ;  // [B,H]

    // workspace carve (bytes), all 16B aligned
    char* w = (char*)d_ws;
    __bf16* x_bf   = (__bf16*)w;  w += (size_t)B_SZ * T_SZ * I_SZ * 2;  // 33.5 MB
    __bf16* wih_bf = (__bf16*)w;  w += (size_t)H_SZ * I_SZ * 2;         // 1 MB
    __bf16* xp_bf  = (__bf16*)w;  w += (size_t)B_SZ * T_SZ * H_SZ * 2;  // 67 MB, [T,B,H]
    __bf16* hA     = (__bf16*)w;  w += (size_t)B_SZ * H_SZ * 2;         // 256 KB
    __bf16* hB     = (__bf16*)w;  w += (size_t)B_SZ * H_SZ * 2;         // 256 KB
    unsigned* cnt  = (unsigned*)w; w += 4096;                           // 8 groups x 2 counters
    (void)ws_size;

    // converts (W_hh converted inline by rnn_persist)
    {
        int n4 = B_SZ * T_SZ * I_SZ / 4;
        cvt_kernel<<<(n4 + 255) / 256, 256, 0, stream>>>(x, x_bf, n4);
    }
    {
        int n4 = H_SZ * I_SZ / 4;
        cvt_kernel<<<(n4 + 255) / 256, 256, 0, stream>>>(Wih, wih_bf, n4);
    }

    // h0 = 0, counters = 0 (ws is re-poisoned 0xAA before every launch)
    hipMemsetAsync(hA, 0, (size_t)B_SZ * H_SZ * 2, stream);
    hipMemsetAsync(cnt, 0, 4096, stream);

    // input projection: 64x128 tiles, hoisted B-regs
    {
        dim3 grid(B_SZ * T_SZ / 64, H_SZ / 128);  // (512, 8)
        proj_kernel<<<grid, 512, 0, stream>>>(x_bf, wih_bf, bih, xp_bf);
    }

    // persistent recurrence: XCD-local groups, split-K dual-counter exchange
    rnn_persist<<<GRID_P, THR_P, 0, stream>>>(Whh, xp_bf, bhh, hA, hB,
                                              states, hlast, cnt);
}